// Round 1
// 340.796 us; speedup vs baseline: 1.0786x; 1.0786x over previous
//
#include <hip/hip_runtime.h>
#include <stdint.h>

typedef __attribute__((ext_vector_type(4))) float floatx4;
typedef __attribute__((ext_vector_type(8))) short shortx8;

#define LN_EPS 1e-5f

__device__ __forceinline__ unsigned short f2b(float f) {
  unsigned u = __builtin_bit_cast(unsigned, f);
  u = (u + 0x7FFFu + ((u >> 16) & 1u)) >> 16;
  return (unsigned short)u;
}
__device__ __forceinline__ float b2f(unsigned short h) {
  return __builtin_bit_cast(float, (unsigned)h << 16);
}

// async global->LDS 16B: lds dest is wave-uniform base; lane i lands at base + i*16
__device__ __forceinline__ void g2l16(const unsigned short* g, unsigned short* l) {
  __builtin_amdgcn_global_load_lds(
      (const __attribute__((address_space(1))) unsigned int*)g,
      (__attribute__((address_space(3))) unsigned int*)l, 16, 0, 0);
}

// ---------------- block reduction helpers (256 threads = 4 waves) -----------
__device__ __forceinline__ float wave_sum(float v) {
#pragma unroll
  for (int o = 32; o; o >>= 1) v += __shfl_down(v, o, 64);
  return v;
}
__device__ __forceinline__ float block_sum(float v, float* s) {
  v = wave_sum(v);
  __syncthreads();
  if ((threadIdx.x & 63) == 0) s[threadIdx.x >> 6] = v;
  __syncthreads();
  return s[0] + s[1] + s[2] + s[3];
}

// ---------------- transpose W_proj (768,1024) f32 -> (1024,768) bf16 --------
__global__ __launch_bounds__(256) void k_transpose_to_bf16(
    const float* __restrict__ in, unsigned short* __restrict__ out, int K, int N) {
  __shared__ float tile[32][33];
  const int k0 = blockIdx.x * 32, n0 = blockIdx.y * 32;
  const int tx = threadIdx.x & 31, ty = threadIdx.x >> 5;
#pragma unroll
  for (int i = 0; i < 32; i += 8)
    tile[ty + i][tx] = in[(long)(k0 + ty + i) * N + n0 + tx];
  __syncthreads();
#pragma unroll
  for (int i = 0; i < 32; i += 8)
    out[(long)(n0 + ty + i) * K + k0 + tx] = f2b(tile[tx][ty + i]);
}

// ---------------- merged transpose of the 3 gate weights (2048x1024) --------
__global__ __launch_bounds__(256) void k_transpose3(
    const float* __restrict__ Wu, const float* __restrict__ Wr,
    const float* __restrict__ Wn, unsigned short* __restrict__ Wtur,
    unsigned short* __restrict__ Wtn) {
  __shared__ float tile[32][33];
  const int which = blockIdx.z;
  const float* in = which == 0 ? Wu : (which == 1 ? Wr : Wn);
  unsigned short* out = which == 0 ? Wtur : (which == 1 ? Wtur + 1024 * 2048 : Wtn);
  const int K = 2048, N = 1024;
  const int k0 = blockIdx.x * 32, n0 = blockIdx.y * 32;
  const int tx = threadIdx.x & 31, ty = threadIdx.x >> 5;
#pragma unroll
  for (int i = 0; i < 32; i += 8)
    tile[ty + i][tx] = in[(long)(k0 + ty + i) * N + n0 + tx];
  __syncthreads();
#pragma unroll
  for (int i = 0; i < 32; i += 8)
    out[(long)(n0 + ty + i) * K + k0 + tx] = f2b(tile[tx][ty + i]);
}

// ---------------- merged f32 -> bf16 convert: prev, toks, W_proj ------------
__global__ __launch_bounds__(256) void k_cvt3(
    const float* __restrict__ prev, unsigned short* __restrict__ psb,
    const float* __restrict__ toks, unsigned short* __restrict__ tokb,
    const float* __restrict__ wp, unsigned short* __restrict__ wpb) {
  const long chunk = (long)blockIdx.x * 256 + threadIdx.x;  // 4 elems per chunk
  const float* src;
  unsigned short* dst;
  long i;
  if (chunk < 262144) { src = prev; dst = psb; i = chunk * 4; }
  else if (chunk < 6553600) { src = toks; dst = tokb; i = (chunk - 262144) * 4; }
  else { src = wp; dst = wpb; i = (chunk - 6553600) * 4; }
  floatx4 v = *(const floatx4*)(src + i);
  unsigned short t4[4];
#pragma unroll
  for (int j = 0; j < 4; j++) t4[j] = f2b(v[j]);
  *(uint2*)(dst + i) = *(uint2*)t4;
}

// ---------------- generic 64x64 MFMA GEMM, BK=64, swizzled, g2l16 -----------
// C[m][n] = A[m][k]*Bt[n][k]; z decomposes to (batch b, k-chunk kc).
// modes: 0: out2 bf16 = exp(v*scale)                     (scores->attnb)
//        1: out2 bf16 = v                                 (pw)
//        3: out f32  = (1-u)*prev + u*tanh(v+bias)       (cand->new_state)
//        5: c<1024: out f32 = sigmoid(v+bias); else out2 bf16 = sigmoid(v+bias2)*psn
//        6: out f32 = v + rowsum[row]*bias2[c]           (proj2->routed)
__global__ __launch_bounds__(256) void k_gemm64(
    const unsigned short* __restrict__ A, long sAb, long sAk, int lda,
    const unsigned short* __restrict__ Bt, long sBb, long sBk, int ldb,
    int K, int nsplit,
    const float* __restrict__ bias, const float* __restrict__ bias2,
    float scale, int mode,
    void* __restrict__ out, int ldc, long sCb, long sCk,
    unsigned short* __restrict__ out2,
    const unsigned short* __restrict__ aux_psn,
    const float* __restrict__ aux_u, const float* __restrict__ aux_prev) {
  __shared__ unsigned short As[64 * 64];
  __shared__ unsigned short Bs[64 * 64];
  const int tid = threadIdx.x;
  const int wave = tid >> 6, lane = tid & 63;
  const int z = blockIdx.z;
  const int b = (nsplit == 2) ? (z >> 1) : z;
  const int kc = (nsplit == 2) ? (z & 1) : 0;
  const int m0 = blockIdx.x * 64, n0 = blockIdx.y * 64;
  const int wm = wave & 1, wn = wave >> 1;
  const int l16 = lane & 15, quad = lane >> 4;
  const int srow8 = lane >> 3;
  const int c8 = ((lane & 7) ^ srow8) * 8;
  const unsigned short* Ab = A + (long)b * sAb + (long)kc * sAk;
  const unsigned short* Bb = Bt + (long)b * sBb + (long)kc * sBk;

  const unsigned short* gA[2];
  const unsigned short* gB[2];
  unsigned short* lA[2];
  unsigned short* lB[2];
#pragma unroll
  for (int j = 0; j < 2; j++) {
    const int rb = wave * 16 + j * 8;
    gA[j] = Ab + (long)(m0 + rb + srow8) * lda + c8;
    gB[j] = Bb + (long)(n0 + rb + srow8) * ldb + c8;
    lA[j] = &As[rb * 64];
    lB[j] = &Bs[rb * 64];
  }
  int offA[2][2], offB[2][2];
#pragma unroll
  for (int ks = 0; ks < 2; ks++)
#pragma unroll
    for (int i = 0; i < 2; i++) {
      int r = wm * 32 + i * 16 + l16;
      offA[ks][i] = r * 64 + (((ks * 4 + quad) ^ (r & 7)) * 8);
      r = wn * 32 + i * 16 + l16;
      offB[ks][i] = r * 64 + (((ks * 4 + quad) ^ (r & 7)) * 8);
    }

  floatx4 acc[2][2] = {};

  for (int k0 = 0; k0 < K; k0 += 64) {
#pragma unroll
    for (int j = 0; j < 2; j++) {
      g2l16(gA[j] + k0, lA[j]);
      g2l16(gB[j] + k0, lB[j]);
    }
    __syncthreads();
#pragma unroll
    for (int ks = 0; ks < 2; ks++) {
      shortx8 af[2], bf[2];
#pragma unroll
      for (int i = 0; i < 2; i++) af[i] = *(const shortx8*)&As[offA[ks][i]];
#pragma unroll
      for (int j = 0; j < 2; j++) bf[j] = *(const shortx8*)&Bs[offB[ks][j]];
#pragma unroll
      for (int i = 0; i < 2; i++)
#pragma unroll
        for (int j = 0; j < 2; j++)
          acc[i][j] = __builtin_amdgcn_mfma_f32_16x16x32_bf16(af[i], bf[j], acc[i][j], 0, 0, 0);
    }
    __syncthreads();
  }

#pragma unroll
  for (int i = 0; i < 2; i++)
#pragma unroll
    for (int j = 0; j < 2; j++) {
      const int rbase = m0 + wm * 32 + i * 16 + quad * 4;
      const int c = n0 + wn * 32 + j * 16 + l16;
      float bval = 0.0f;
      if (bias) bval = (mode == 5 && c >= 1024) ? bias2[c - 1024] : bias[c];
#pragma unroll
      for (int r = 0; r < 4; r++) {
        const int row = rbase + r;
        float v = acc[i][j][r] * scale + bval;
        const long cidx = (long)b * sCb + (long)kc * sCk + (long)row * ldc + c;
        if (mode == 0) {
          out2[cidx] = f2b(expf(v));
        } else if (mode == 1) {
          out2[cidx] = f2b(v);
        } else if (mode == 3) {
          float cand = tanhf(v);
          float u = aux_u[(long)row * 1024 + c];
          float p = aux_prev[(long)row * 1024 + c];
          ((float*)out)[cidx] = (1.0f - u) * p + u * cand;
        } else if (mode == 6) {
          ((float*)out)[cidx] = v + aux_u[row] * bias2[c];
        } else {  // mode 5
          if (c < 1024) {
            ((float*)out)[(long)row * 1024 + c] = 1.0f / (1.0f + expf(-v));
          } else {
            const int cc = c - 1024;
            float rr = 1.0f / (1.0f + expf(-v));
            out2[(long)row * 2048 + cc] = f2b(rr * b2f(aux_psn[(long)row * 2048 + cc]));
          }
        }
      }
    }
}

// ---------------- rw = attnb(exp) @ tokens via MFMA, K-split x2 -------------
// attnb [16][64][2048] bf16, tokb [16][2048][768] bf16 -> parts [2][1024][768] f32
__global__ __launch_bounds__(256) void k_routed_mfma(
    const unsigned short* __restrict__ attnb,
    const unsigned short* __restrict__ tok,
    float* __restrict__ parts) {
  __shared__ unsigned short As[64 * 40];
  __shared__ unsigned short Bs[32 * 66];
  const int kc = blockIdx.x, nt = blockIdx.y, b = blockIdx.z;
  const int tid = threadIdx.x;
  const int wave = tid >> 6, lane = tid & 63;
  const int wm = wave & 1, wn = wave >> 1;
  const int l16 = lane & 15, quad = lane >> 4;
  const int n0 = nt * 64;
  const long abase = (long)b * 131072 + (long)kc * 1024;
  const long tbase = ((long)b * 2048 + (long)kc * 1024) * 768;
  const int srow = tid >> 2, skc = (tid & 3) * 8;
  const int bk = tid >> 3, bd = (tid & 7) * 8;

  floatx4 acc[2][2] = {};

  for (int k0 = 0; k0 < 1024; k0 += 32) {
    *(uint4*)&As[srow * 40 + skc] =
        *(const uint4*)(attnb + abase + (long)srow * 2048 + k0 + skc);
    {
      uint4 v = *(const uint4*)(tok + tbase + (long)(k0 + bk) * 768 + n0 + bd);
      const unsigned* pv = (const unsigned*)&v;
      unsigned short* dst = &Bs[bk * 66 + bd];
#pragma unroll
      for (int w2 = 0; w2 < 4; w2++) *(unsigned*)(dst + w2 * 2) = pv[w2];
    }
    __syncthreads();

    shortx8 a0 = *(const shortx8*)&As[(wm * 32 + 0  + l16) * 40 + quad * 8];
    shortx8 a1 = *(const shortx8*)&As[(wm * 32 + 16 + l16) * 40 + quad * 8];
    shortx8 b0, b1;
#pragma unroll
    for (int j = 0; j < 8; j++) {
      b0[j] = *(const short*)&Bs[(quad * 8 + j) * 66 + wn * 32 + l16];
      b1[j] = *(const short*)&Bs[(quad * 8 + j) * 66 + wn * 32 + 16 + l16];
    }
    acc[0][0] = __builtin_amdgcn_mfma_f32_16x16x32_bf16(a0, b0, acc[0][0], 0, 0, 0);
    acc[0][1] = __builtin_amdgcn_mfma_f32_16x16x32_bf16(a0, b1, acc[0][1], 0, 0, 0);
    acc[1][0] = __builtin_amdgcn_mfma_f32_16x16x32_bf16(a1, b0, acc[1][0], 0, 0, 0);
    acc[1][1] = __builtin_amdgcn_mfma_f32_16x16x32_bf16(a1, b1, acc[1][1], 0, 0, 0);
    __syncthreads();
  }

#pragma unroll
  for (int im = 0; im < 2; im++)
#pragma unroll
    for (int in_ = 0; in_ < 2; in_++) {
      const int rbase = wm * 32 + im * 16 + quad * 4;
      const int c = n0 + wn * 32 + in_ * 16 + l16;
#pragma unroll
      for (int r = 0; r < 4; r++)
        parts[(long)kc * 786432 + ((long)b * 64 + rbase + r) * 768 + c] =
            acc[im][in_][r];
    }
}

// ---------------- rowsum of exp weights (for b_proj reconstruction) ---------
__global__ __launch_bounds__(256) void k_rowsum(
    const unsigned short* __restrict__ w, float* __restrict__ rs) {
  __shared__ float scr[4];
  const long r = blockIdx.x;
  const int t = threadIdx.x;
  uint4 v = *(const uint4*)(w + r * 2048 + t * 8);
  const unsigned short* h = (const unsigned short*)&v;
  float s = 0.0f;
#pragma unroll
  for (int i = 0; i < 8; i++) s += b2f(h[i]);
  s = block_sum(s, scr);
  if (t == 0) rs[r] = s;
}

// ---------------- sum the 2 k-split parts, convert to bf16 ------------------
__global__ __launch_bounds__(256) void k_sumcvt(
    const float* __restrict__ parts, unsigned short* __restrict__ out) {
  const long i = ((long)blockIdx.x * 256 + threadIdx.x) * 4;
  floatx4 v = *(const floatx4*)(parts + i);
  floatx4 w = *(const floatx4*)(parts + 786432 + i);
  unsigned short t4[4];
#pragma unroll
  for (int j = 0; j < 4; j++) t4[j] = f2b(v[j] + w[j]);
  *(uint2*)(out + i) = *(uint2*)t4;
}

// ---------------- merged LayerNorms: prev->conc[:, :D], routed->conc/candA --
// LN is scale-invariant, so unnormalized exp-weighted routed is fine.
__global__ __launch_bounds__(256) void k_ln2(
    const float* __restrict__ prev, const float* __restrict__ routed,
    const float* __restrict__ g_st, const float* __restrict__ be_st,
    const float* __restrict__ g_in, const float* __restrict__ be_in,
    unsigned short* __restrict__ conc, unsigned short* __restrict__ candA) {
  __shared__ float scr[4];
  const long r = blockIdx.x & 1023;
  const bool second = blockIdx.x >= 1024;
  const int t = threadIdx.x;
  floatx4 v;
  const float *g, *be;
  if (!second) {
    v = *(const floatx4*)(prev + r * 1024 + t * 4);
    g = g_st; be = be_st;
  } else {
    v = *(const floatx4*)(routed + r * 1024 + t * 4);
    g = g_in; be = be_in;
  }
  float s1 = v[0] + v[1] + v[2] + v[3];
  float s2 = v[0] * v[0] + v[1] * v[1] + v[2] * v[2] + v[3] * v[3];
  s1 = block_sum(s1, scr);
  s2 = block_sum(s2, scr);
  const float mean = s1 * (1.0f / 1024.0f);
  const float var = s2 * (1.0f / 1024.0f) - mean * mean;
  const float rstd = rsqrtf(var + LN_EPS);
#pragma unroll
  for (int i = 0; i < 4; i++) {
    const int d = t * 4 + i;
    const float y = (v[i] - mean) * rstd * g[d] + be[d];
    const unsigned short h = f2b(y);
    if (!second) {
      conc[r * 2048 + d] = h;
    } else {
      conc[r * 2048 + 1024 + d] = h;
      candA[r * 2048 + 1024 + d] = h;
    }
  }
}

// ---------------- final LayerNorm -> f32 output ------------------------------
__global__ __launch_bounds__(256) void k_ln_out(
    const float* __restrict__ in, const float* __restrict__ g,
    const float* __restrict__ be, float* __restrict__ out) {
  __shared__ float scr[4];
  const long r = blockIdx.x;
  const int t = threadIdx.x;
  floatx4 v = *(const floatx4*)(in + r * 1024 + t * 4);
  float s1 = v[0] + v[1] + v[2] + v[3];
  float s2 = v[0] * v[0] + v[1] * v[1] + v[2] * v[2] + v[3] * v[3];
  s1 = block_sum(s1, scr);
  s2 = block_sum(s2, scr);
  const float mean = s1 * (1.0f / 1024.0f);
  const float var = s2 * (1.0f / 1024.0f) - mean * mean;
  const float rstd = rsqrtf(var + LN_EPS);
  floatx4 o;
#pragma unroll
  for (int i = 0; i < 4; i++) {
    const int d = t * 4 + i;
    o[i] = (v[i] - mean) * rstd * g[d] + be[d];
  }
  *(floatx4*)(out + r * 1024 + t * 4) = o;
}

// ---------------------------------------------------------------------------
extern "C" void kernel_launch(void* const* d_in, const int* in_sizes, int n_in,
                              void* d_out, int out_size, void* d_ws, size_t ws_size,
                              hipStream_t stream) {
  (void)in_sizes; (void)n_in; (void)out_size; (void)ws_size;
  const float* prev  = (const float*)d_in[0];
  const float* toks  = (const float*)d_in[1];
  const float* Wp    = (const float*)d_in[2];
  const float* bp    = (const float*)d_in[3];
  const float* g_st  = (const float*)d_in[4];
  const float* be_st = (const float*)d_in[5];
  const float* g_in  = (const float*)d_in[6];
  const float* be_in = (const float*)d_in[7];
  const float* g_o   = (const float*)d_in[8];
  const float* be_o  = (const float*)d_in[9];
  const float* Wu    = (const float*)d_in[10];
  const float* bu    = (const float*)d_in[11];
  const float* Wr    = (const float*)d_in[12];
  const float* br    = (const float*)d_in[13];
  const float* Wn    = (const float*)d_in[14];
  const float* bn    = (const float*)d_in[15];
  float* out = (float*)d_out;

  // ---- workspace (~103 MB), no aliasing needed anymore
  char* ws = (char*)d_ws;
  unsigned short* tokb  = (unsigned short*)ws; ws += 50331648;  // 32768x768 bf16
  unsigned short* psb   = (unsigned short*)ws; ws += 2097152;   // 1024x1024 bf16
  unsigned short* Wpb   = (unsigned short*)ws; ws += 1572864;   // 768x1024 bf16
  unsigned short* Wtp   = (unsigned short*)ws; ws += 1572864;   // 1024x768 bf16
  unsigned short* pwb   = (unsigned short*)ws; ws += 1572864;   // 1024x768 bf16
  unsigned short* attnb = (unsigned short*)ws; ws += 4194304;   // 16x64x2048 bf16
  float*          rowsum= (float*)ws;          ws += 4096;      // 1024 f32
  float*          parts = (float*)ws;          ws += 6291456;   // 2x 1024x768 f32
  unsigned short* rwb   = (unsigned short*)ws; ws += 1572864;   // 1024x768 bf16
  float*          routed= (float*)ws;          ws += 4194304;   // 1024x1024 f32
  unsigned short* conc  = (unsigned short*)ws; ws += 4194304;   // 1024x2048 bf16
  unsigned short* candA = (unsigned short*)ws; ws += 4194304;   // 1024x2048 bf16
  float*          ubuf  = (float*)ws;          ws += 4194304;   // 1024x1024 f32
  float*          ns    = (float*)ws;          ws += 4194304;   // 1024x1024 f32
  unsigned short* Wtur  = (unsigned short*)ws; ws += 8388608;   // 2048x2048 bf16
  unsigned short* Wtn   = (unsigned short*)ws; ws += 4194304;   // 1024x2048 bf16

  const dim3 blk(256);

  // 1. prev, toks, W_proj -> bf16 (one launch)
  k_cvt3<<<dim3(26368), blk, 0, stream>>>(prev, psb, toks, tokb, Wp, Wpb);
  // 2. W_proj^T (for proj2's Bt)
  k_transpose_to_bf16<<<dim3(24, 32), blk, 0, stream>>>(Wp, Wtp, 768, 1024);
  // 3. gate weight transposes
  k_transpose3<<<dim3(64, 32, 3), blk, 0, stream>>>(Wu, Wr, Wn, Wtur, Wtn);
  // 4. pw = prev @ W_proj^T  (M=1024, N=768, K=1024) -> bf16 (mode 1)
  k_gemm64<<<dim3(16, 12, 1), blk, 0, stream>>>(
      psb, 0L, 0L, 1024, Wpb, 0L, 0L, 1024, 1024, 1,
      nullptr, nullptr, 1.0f, 1,
      nullptr, 768, 0L, 0L, pwb, nullptr, nullptr, nullptr);
  // 5. attnb = exp(pw @ tokens^T / 32)  (mode 0; softmax denom dropped; the
  //    prev.b_proj score term is constant over s -> cancels in softmax)
  k_gemm64<<<dim3(1, 32, 16), blk, 0, stream>>>(
      pwb, 49152L, 0L, 768, tokb, 1572864L, 0L, 768, 768, 1,
      nullptr, nullptr, 0.03125f, 0,
      nullptr, 2048, 131072L, 0L, attnb, nullptr, nullptr, nullptr);
  // 6. rowsum of exp weights (reconstructs Sum(w)*b_proj exactly)
  k_rowsum<<<dim3(1024), blk, 0, stream>>>(attnb, rowsum);
  // 7. rw partials = w @ tokens (unnormalized), K-split x2
  k_routed_mfma<<<dim3(2, 12, 16), blk, 0, stream>>>(attnb, tokb, parts);
  // 8. sum parts -> rwb bf16
  k_sumcvt<<<dim3(768), blk, 0, stream>>>(parts, rwb);
  // 9. routed = rw @ W_proj + rowsum*b_proj  (M=1024, N=1024, K=768, mode 6)
  k_gemm64<<<dim3(16, 16, 1), blk, 0, stream>>>(
      rwb, 0L, 0L, 768, Wtp, 0L, 0L, 768, 768, 1,
      nullptr, bp, 1.0f, 6,
      (void*)routed, 1024, 0L, 0L, nullptr, nullptr, rowsum, nullptr);
  // 10. both LayerNorms
  k_ln2<<<dim3(2048), blk, 0, stream>>>(prev, routed, g_st, be_st, g_in, be_in,
                                        conc, candA);
  // 11. merged u|r gates (mode 5)
  k_gemm64<<<dim3(16, 32, 1), blk, 0, stream>>>(
      conc, 0L, 0L, 2048, Wtur, 0L, 0L, 2048, 2048, 1,
      bu, br, 1.0f, 5,
      (void*)ubuf, 1024, 0L, 0L, candA, conc, nullptr, nullptr);
  // 12. new_state (mode 3)
  k_gemm64<<<dim3(16, 16, 1), blk, 0, stream>>>(
      candA, 0L, 0L, 2048, Wtn, 0L, 0L, 2048, 2048, 1,
      bn, nullptr, 1.0f, 3,
      (void*)ns, 1024, 0L, 0L, nullptr, nullptr, ubuf, prev);
  // 13. final LN -> output
  k_ln_out<<<dim3(1024), blk, 0, stream>>>(ns, g_o, be_o, out);
}

// Round 2
// 330.909 us; speedup vs baseline: 1.1108x; 1.0299x over previous
//
#include <hip/hip_runtime.h>
#include <stdint.h>

typedef __attribute__((ext_vector_type(4))) float floatx4;
typedef __attribute__((ext_vector_type(8))) short shortx8;

#define LN_EPS 1e-5f

__device__ __forceinline__ unsigned short f2b(float f) {
  unsigned u = __builtin_bit_cast(unsigned, f);
  u = (u + 0x7FFFu + ((u >> 16) & 1u)) >> 16;
  return (unsigned short)u;
}
__device__ __forceinline__ float b2f(unsigned short h) {
  return __builtin_bit_cast(float, (unsigned)h << 16);
}

// async global->LDS 16B: lds dest is wave-uniform base; lane i lands at base + i*16
__device__ __forceinline__ void g2l16(const unsigned short* g, unsigned short* l) {
  __builtin_amdgcn_global_load_lds(
      (const __attribute__((address_space(1))) unsigned int*)g,
      (__attribute__((address_space(3))) unsigned int*)l, 16, 0, 0);
}

// ---------------- block reduction helpers (256 threads = 4 waves) -----------
__device__ __forceinline__ float wave_sum(float v) {
#pragma unroll
  for (int o = 32; o; o >>= 1) v += __shfl_down(v, o, 64);
  return v;
}
__device__ __forceinline__ float block_sum(float v, float* s) {
  v = wave_sum(v);
  __syncthreads();
  if ((threadIdx.x & 63) == 0) s[threadIdx.x >> 6] = v;
  __syncthreads();
  return s[0] + s[1] + s[2] + s[3];
}

// ---------------- merged transpose of all 4 weights -------------------------
// which 0..2: gate weights (2048x1024); which 3: W_proj (768x1024)
__global__ __launch_bounds__(256) void k_transpose4(
    const float* __restrict__ Wu, const float* __restrict__ Wr,
    const float* __restrict__ Wn, const float* __restrict__ Wp,
    unsigned short* __restrict__ Wtur, unsigned short* __restrict__ Wtn,
    unsigned short* __restrict__ Wtp) {
  __shared__ float tile[32][33];
  const int which = blockIdx.z;
  const float* in;
  unsigned short* out;
  int K;
  if (which == 0)      { in = Wu; out = Wtur;              K = 2048; }
  else if (which == 1) { in = Wr; out = Wtur + 1024 * 2048; K = 2048; }
  else if (which == 2) { in = Wn; out = Wtn;               K = 2048; }
  else                 { in = Wp; out = Wtp;               K = 768;  }
  const int N = 1024;
  const int k0 = blockIdx.x * 32, n0 = blockIdx.y * 32;
  if (k0 >= K) return;
  const int tx = threadIdx.x & 31, ty = threadIdx.x >> 5;
#pragma unroll
  for (int i = 0; i < 32; i += 8)
    tile[ty + i][tx] = in[(long)(k0 + ty + i) * N + n0 + tx];
  __syncthreads();
#pragma unroll
  for (int i = 0; i < 32; i += 8)
    out[(long)(n0 + ty + i) * K + k0 + tx] = f2b(tile[tx][ty + i]);
}

// ---------------- merged f32 -> bf16 convert: prev, toks, W_proj ------------
// block 0 additionally zeroes the rowsum accumulator (1024 f32)
__global__ __launch_bounds__(256) void k_cvt3(
    const float* __restrict__ prev, unsigned short* __restrict__ psb,
    const float* __restrict__ toks, unsigned short* __restrict__ tokb,
    const float* __restrict__ wp, unsigned short* __restrict__ wpb,
    float* __restrict__ rs) {
  if (blockIdx.x == 0) {
    floatx4 z = {0.f, 0.f, 0.f, 0.f};
    *(floatx4*)(rs + threadIdx.x * 4) = z;
  }
  const long chunk = (long)blockIdx.x * 256 + threadIdx.x;  // 4 elems per chunk
  const float* src;
  unsigned short* dst;
  long i;
  if (chunk < 262144) { src = prev; dst = psb; i = chunk * 4; }
  else if (chunk < 6553600) { src = toks; dst = tokb; i = (chunk - 262144) * 4; }
  else { src = wp; dst = wpb; i = (chunk - 6553600) * 4; }
  floatx4 v = *(const floatx4*)(src + i);
  unsigned short t4[4];
#pragma unroll
  for (int j = 0; j < 4; j++) t4[j] = f2b(v[j]);
  *(uint2*)(dst + i) = *(uint2*)t4;
}

// ---------------- generic 64x64 MFMA GEMM, BK=64, double-buffered ----------
// C[m][n] = A[m][k]*Bt[n][k]; z = batch b.
// modes: 0: out2 bf16 = exp(v*scale); rowsum atomically accumulated into rs
//        1: out2 bf16 = v                                 (pw)
//        3: out f32  = (1-u)*prev + u*tanh(v+bias)       (cand->new_state)
//        5: c<1024: out f32 = sigmoid(v+bias); else out2 bf16 = sigmoid(v+bias2)*psn
//        6: out f32 = v + rowsum[row]*bias2[c]           (proj2->routed)
__global__ __launch_bounds__(256) void k_gemm64(
    const unsigned short* __restrict__ A, long sAb, int lda,
    const unsigned short* __restrict__ Bt, long sBb, int ldb,
    int K,
    const float* __restrict__ bias, const float* __restrict__ bias2,
    float scale, int mode,
    void* __restrict__ out, int ldc, long sCb,
    unsigned short* __restrict__ out2,
    const unsigned short* __restrict__ aux_psn,
    const float* __restrict__ aux_u, const float* __restrict__ aux_prev,
    float* __restrict__ rs) {
  __shared__ unsigned short As[2][64 * 64];
  __shared__ unsigned short Bs[2][64 * 64];
  const int tid = threadIdx.x;
  const int wave = tid >> 6, lane = tid & 63;
  const int b = blockIdx.z;
  const int m0 = blockIdx.x * 64, n0 = blockIdx.y * 64;
  const int wm = wave & 1, wn = wave >> 1;
  const int l16 = lane & 15, quad = lane >> 4;
  const int srow8 = lane >> 3;
  const int c8 = ((lane & 7) ^ srow8) * 8;
  const unsigned short* Ab = A + (long)b * sAb;
  const unsigned short* Bb = Bt + (long)b * sBb;

  const unsigned short* gA[2];
  const unsigned short* gB[2];
  int lAoff[2], lBoff[2];
#pragma unroll
  for (int j = 0; j < 2; j++) {
    const int rb = wave * 16 + j * 8;
    gA[j] = Ab + (long)(m0 + rb + srow8) * lda + c8;
    gB[j] = Bb + (long)(n0 + rb + srow8) * ldb + c8;
    lAoff[j] = rb * 64;
    lBoff[j] = rb * 64;
  }
  int offA[2][2], offB[2][2];
#pragma unroll
  for (int ks = 0; ks < 2; ks++)
#pragma unroll
    for (int i = 0; i < 2; i++) {
      int r = wm * 32 + i * 16 + l16;
      offA[ks][i] = r * 64 + (((ks * 4 + quad) ^ (r & 7)) * 8);
      r = wn * 32 + i * 16 + l16;
      offB[ks][i] = r * 64 + (((ks * 4 + quad) ^ (r & 7)) * 8);
    }

  floatx4 acc[2][2] = {};

  // prologue: stage tile 0 into buffer 0
#pragma unroll
  for (int j = 0; j < 2; j++) {
    g2l16(gA[j], &As[0][lAoff[j]]);
    g2l16(gB[j], &Bs[0][lBoff[j]]);
  }
  __syncthreads();

  const int nt = K >> 6;
  for (int t = 0; t < nt; t++) {
    const int cur = t & 1;
    if (t + 1 < nt) {
      const int kn = (t + 1) << 6;
#pragma unroll
      for (int j = 0; j < 2; j++) {
        g2l16(gA[j] + kn, &As[cur ^ 1][lAoff[j]]);
        g2l16(gB[j] + kn, &Bs[cur ^ 1][lBoff[j]]);
      }
    }
#pragma unroll
    for (int ks = 0; ks < 2; ks++) {
      shortx8 af[2], bf[2];
#pragma unroll
      for (int i = 0; i < 2; i++) af[i] = *(const shortx8*)&As[cur][offA[ks][i]];
#pragma unroll
      for (int j = 0; j < 2; j++) bf[j] = *(const shortx8*)&Bs[cur][offB[ks][j]];
#pragma unroll
      for (int i = 0; i < 2; i++)
#pragma unroll
        for (int j = 0; j < 2; j++)
          acc[i][j] = __builtin_amdgcn_mfma_f32_16x16x32_bf16(af[i], bf[j], acc[i][j], 0, 0, 0);
    }
    __syncthreads();  // implicit vmcnt(0): drains next-tile loads issued above
  }

  if (mode == 0) {
#pragma unroll
    for (int i = 0; i < 2; i++) {
      float psum[4] = {0.f, 0.f, 0.f, 0.f};
#pragma unroll
      for (int j = 0; j < 2; j++) {
        const int rbase = m0 + wm * 32 + i * 16 + quad * 4;
        const int c = n0 + wn * 32 + j * 16 + l16;
#pragma unroll
        for (int r = 0; r < 4; r++) {
          const float e = expf(acc[i][j][r] * scale);
          out2[(long)b * sCb + (long)(rbase + r) * ldc + c] = f2b(e);
          psum[r] += e;
        }
      }
#pragma unroll
      for (int r = 0; r < 4; r++) {
        float s = psum[r];
        s += __shfl_xor(s, 1, 64);
        s += __shfl_xor(s, 2, 64);
        s += __shfl_xor(s, 4, 64);
        s += __shfl_xor(s, 8, 64);
        if (l16 == 0)
          atomicAdd(rs + (long)b * 64 + m0 + wm * 32 + i * 16 + quad * 4 + r, s);
      }
    }
    return;
  }

#pragma unroll
  for (int i = 0; i < 2; i++)
#pragma unroll
    for (int j = 0; j < 2; j++) {
      const int rbase = m0 + wm * 32 + i * 16 + quad * 4;
      const int c = n0 + wn * 32 + j * 16 + l16;
      float bval = 0.0f;
      if (bias) bval = (mode == 5 && c >= 1024) ? bias2[c - 1024] : bias[c];
#pragma unroll
      for (int r = 0; r < 4; r++) {
        const int row = rbase + r;
        float v = acc[i][j][r] * scale + bval;
        const long cidx = (long)b * sCb + (long)row * ldc + c;
        if (mode == 1) {
          out2[cidx] = f2b(v);
        } else if (mode == 3) {
          float cand = tanhf(v);
          float u = aux_u[(long)row * 1024 + c];
          float p = aux_prev[(long)row * 1024 + c];
          ((float*)out)[cidx] = (1.0f - u) * p + u * cand;
        } else if (mode == 6) {
          ((float*)out)[cidx] = v + aux_u[row] * bias2[c];
        } else {  // mode 5
          if (c < 1024) {
            ((float*)out)[(long)row * 1024 + c] = 1.0f / (1.0f + expf(-v));
          } else {
            const int cc = c - 1024;
            float rr = 1.0f / (1.0f + expf(-v));
            out2[(long)row * 2048 + cc] = f2b(rr * b2f(aux_psn[(long)row * 2048 + cc]));
          }
        }
      }
    }
}

// ---------------- rw = attnb(exp) @ tokens via MFMA, K-split x2 -------------
// attnb [16][64][2048] bf16, tokb [16][2048][768] bf16 -> parts [2][1024][768] f32
// async-STAGE: next-tile global loads stay in flight across raw barriers.
__global__ __launch_bounds__(256) void k_routed_mfma(
    const unsigned short* __restrict__ attnb,
    const unsigned short* __restrict__ tok,
    float* __restrict__ parts) {
  __shared__ unsigned short As[64 * 40];
  __shared__ unsigned short Bs[32 * 66];
  const int kc = blockIdx.x, nt = blockIdx.y, b = blockIdx.z;
  const int tid = threadIdx.x;
  const int wave = tid >> 6, lane = tid & 63;
  const int wm = wave & 1, wn = wave >> 1;
  const int l16 = lane & 15, quad = lane >> 4;
  const int n0 = nt * 64;
  const long abase = (long)b * 131072 + (long)kc * 1024;
  const long tbase = ((long)b * 2048 + (long)kc * 1024) * 768;
  const int srow = tid >> 2, skc = (tid & 3) * 8;
  const int bk = tid >> 3, bd = (tid & 7) * 8;

  floatx4 acc[2][2] = {};

  // prefetch tile 0 into registers
  uint4 pa = *(const uint4*)(attnb + abase + (long)srow * 2048 + skc);
  uint4 pb = *(const uint4*)(tok + tbase + (long)bk * 768 + n0 + bd);

  for (int k0 = 0; k0 < 1024; k0 += 32) {
    // write staged regs to LDS (compiler inserts the vmcnt wait here)
    *(uint4*)&As[srow * 40 + skc] = pa;
    {
      const unsigned* pv = (const unsigned*)&pb;
      unsigned short* dst = &Bs[bk * 66 + bd];
#pragma unroll
      for (int w2 = 0; w2 < 4; w2++) *(unsigned*)(dst + w2 * 2) = pv[w2];
    }
    // issue next-tile loads; they stay in flight across the barriers below
    if (k0 + 32 < 1024) {
      pa = *(const uint4*)(attnb + abase + (long)srow * 2048 + (k0 + 32) + skc);
      pb = *(const uint4*)(tok + tbase + (long)(k0 + 32 + bk) * 768 + n0 + bd);
    }
    asm volatile("s_waitcnt lgkmcnt(0)" ::: "memory");
    __builtin_amdgcn_s_barrier();
    __builtin_amdgcn_sched_barrier(0);

    shortx8 a0 = *(const shortx8*)&As[(wm * 32 + 0  + l16) * 40 + quad * 8];
    shortx8 a1 = *(const shortx8*)&As[(wm * 32 + 16 + l16) * 40 + quad * 8];
    shortx8 b0, b1;
#pragma unroll
    for (int j = 0; j < 8; j++) {
      b0[j] = *(const short*)&Bs[(quad * 8 + j) * 66 + wn * 32 + l16];
      b1[j] = *(const short*)&Bs[(quad * 8 + j) * 66 + wn * 32 + 16 + l16];
    }
    acc[0][0] = __builtin_amdgcn_mfma_f32_16x16x32_bf16(a0, b0, acc[0][0], 0, 0, 0);
    acc[0][1] = __builtin_amdgcn_mfma_f32_16x16x32_bf16(a0, b1, acc[0][1], 0, 0, 0);
    acc[1][0] = __builtin_amdgcn_mfma_f32_16x16x32_bf16(a1, b0, acc[1][0], 0, 0, 0);
    acc[1][1] = __builtin_amdgcn_mfma_f32_16x16x32_bf16(a1, b1, acc[1][1], 0, 0, 0);
    __builtin_amdgcn_s_barrier();  // all waves done reading LDS before overwrite
  }

#pragma unroll
  for (int im = 0; im < 2; im++)
#pragma unroll
    for (int in_ = 0; in_ < 2; in_++) {
      const int rbase = wm * 32 + im * 16 + quad * 4;
      const int c = n0 + wn * 32 + in_ * 16 + l16;
#pragma unroll
      for (int r = 0; r < 4; r++)
        parts[(long)kc * 786432 + ((long)b * 64 + rbase + r) * 768 + c] =
            acc[im][in_][r];
    }
}

// ---------------- sum the 2 k-split parts, convert to bf16 ------------------
__global__ __launch_bounds__(256) void k_sumcvt(
    const float* __restrict__ parts, unsigned short* __restrict__ out) {
  const long i = ((long)blockIdx.x * 256 + threadIdx.x) * 4;
  floatx4 v = *(const floatx4*)(parts + i);
  floatx4 w = *(const floatx4*)(parts + 786432 + i);
  unsigned short t4[4];
#pragma unroll
  for (int j = 0; j < 4; j++) t4[j] = f2b(v[j] + w[j]);
  *(uint2*)(out + i) = *(uint2*)t4;
}

// ---------------- merged LayerNorms: prev->conc[:, :D], routed->conc/candA --
__global__ __launch_bounds__(256) void k_ln2(
    const float* __restrict__ prev, const float* __restrict__ routed,
    const float* __restrict__ g_st, const float* __restrict__ be_st,
    const float* __restrict__ g_in, const float* __restrict__ be_in,
    unsigned short* __restrict__ conc, unsigned short* __restrict__ candA) {
  __shared__ float scr[4];
  const long r = blockIdx.x & 1023;
  const bool second = blockIdx.x >= 1024;
  const int t = threadIdx.x;
  floatx4 v;
  const float *g, *be;
  if (!second) {
    v = *(const floatx4*)(prev + r * 1024 + t * 4);
    g = g_st; be = be_st;
  } else {
    v = *(const floatx4*)(routed + r * 1024 + t * 4);
    g = g_in; be = be_in;
  }
  float s1 = v[0] + v[1] + v[2] + v[3];
  float s2 = v[0] * v[0] + v[1] * v[1] + v[2] * v[2] + v[3] * v[3];
  s1 = block_sum(s1, scr);
  s2 = block_sum(s2, scr);
  const float mean = s1 * (1.0f / 1024.0f);
  const float var = s2 * (1.0f / 1024.0f) - mean * mean;
  const float rstd = rsqrtf(var + LN_EPS);
#pragma unroll
  for (int i = 0; i < 4; i++) {
    const int d = t * 4 + i;
    const float y = (v[i] - mean) * rstd * g[d] + be[d];
    const unsigned short h = f2b(y);
    if (!second) {
      conc[r * 2048 + d] = h;
    } else {
      conc[r * 2048 + 1024 + d] = h;
      candA[r * 2048 + 1024 + d] = h;
    }
  }
}

// ---------------- final LayerNorm -> f32 output ------------------------------
__global__ __launch_bounds__(256) void k_ln_out(
    const float* __restrict__ in, const float* __restrict__ g,
    const float* __restrict__ be, float* __restrict__ out) {
  __shared__ float scr[4];
  const long r = blockIdx.x;
  const int t = threadIdx.x;
  floatx4 v = *(const floatx4*)(in + r * 1024 + t * 4);
  float s1 = v[0] + v[1] + v[2] + v[3];
  float s2 = v[0] * v[0] + v[1] * v[1] + v[2] * v[2] + v[3] * v[3];
  s1 = block_sum(s1, scr);
  s2 = block_sum(s2, scr);
  const float mean = s1 * (1.0f / 1024.0f);
  const float var = s2 * (1.0f / 1024.0f) - mean * mean;
  const float rstd = rsqrtf(var + LN_EPS);
  floatx4 o;
#pragma unroll
  for (int i = 0; i < 4; i++) {
    const int d = t * 4 + i;
    o[i] = (v[i] - mean) * rstd * g[d] + be[d];
  }
  *(floatx4*)(out + r * 1024 + t * 4) = o;
}

// ---------------------------------------------------------------------------
extern "C" void kernel_launch(void* const* d_in, const int* in_sizes, int n_in,
                              void* d_out, int out_size, void* d_ws, size_t ws_size,
                              hipStream_t stream) {
  (void)in_sizes; (void)n_in; (void)out_size; (void)ws_size;
  const float* prev  = (const float*)d_in[0];
  const float* toks  = (const float*)d_in[1];
  const float* Wp    = (const float*)d_in[2];
  const float* bp    = (const float*)d_in[3];
  const float* g_st  = (const float*)d_in[4];
  const float* be_st = (const float*)d_in[5];
  const float* g_in  = (const float*)d_in[6];
  const float* be_in = (const float*)d_in[7];
  const float* g_o   = (const float*)d_in[8];
  const float* be_o  = (const float*)d_in[9];
  const float* Wu    = (const float*)d_in[10];
  const float* bu    = (const float*)d_in[11];
  const float* Wr    = (const float*)d_in[12];
  const float* br    = (const float*)d_in[13];
  const float* Wn    = (const float*)d_in[14];
  const float* bn    = (const float*)d_in[15];
  float* out = (float*)d_out;

  // ---- workspace (~103 MB)
  char* ws = (char*)d_ws;
  unsigned short* tokb  = (unsigned short*)ws; ws += 50331648;  // 32768x768 bf16
  unsigned short* psb   = (unsigned short*)ws; ws += 2097152;   // 1024x1024 bf16
  unsigned short* Wpb   = (unsigned short*)ws; ws += 1572864;   // 768x1024 bf16
  unsigned short* Wtp   = (unsigned short*)ws; ws += 1572864;   // 1024x768 bf16
  unsigned short* pwb   = (unsigned short*)ws; ws += 1572864;   // 1024x768 bf16
  unsigned short* attnb = (unsigned short*)ws; ws += 4194304;   // 16x64x2048 bf16
  float*          rowsum= (float*)ws;          ws += 4096;      // 1024 f32
  float*          parts = (float*)ws;          ws += 6291456;   // 2x 1024x768 f32
  unsigned short* rwb   = (unsigned short*)ws; ws += 1572864;   // 1024x768 bf16
  float*          routed= (float*)ws;          ws += 4194304;   // 1024x1024 f32
  unsigned short* conc  = (unsigned short*)ws; ws += 4194304;   // 1024x2048 bf16
  unsigned short* candA = (unsigned short*)ws; ws += 4194304;   // 1024x2048 bf16
  float*          ubuf  = (float*)ws;          ws += 4194304;   // 1024x1024 f32
  float*          ns    = (float*)ws;          ws += 4194304;   // 1024x1024 f32
  unsigned short* Wtur  = (unsigned short*)ws; ws += 8388608;   // 2048x2048 bf16
  unsigned short* Wtn   = (unsigned short*)ws; ws += 4194304;   // 1024x2048 bf16

  const dim3 blk(256);

  // 1. prev, toks, W_proj -> bf16; zero rowsum
  k_cvt3<<<dim3(26368), blk, 0, stream>>>(prev, psb, toks, tokb, Wp, Wpb, rowsum);
  // 2. all weight transposes in one launch
  k_transpose4<<<dim3(64, 32, 4), blk, 0, stream>>>(Wu, Wr, Wn, Wp, Wtur, Wtn, Wtp);
  // 3. pw = prev @ W_proj^T  (M=1024, N=768, K=1024) -> bf16 (mode 1)
  k_gemm64<<<dim3(16, 12, 1), blk, 0, stream>>>(
      psb, 0L, 1024, Wpb, 0L, 1024, 1024,
      nullptr, nullptr, 1.0f, 1,
      nullptr, 768, 0L, pwb, nullptr, nullptr, nullptr, nullptr);
  // 4. attnb = exp(pw @ tokens^T / 32) (mode 0) + fused rowsum atomics
  k_gemm64<<<dim3(1, 32, 16), blk, 0, stream>>>(
      pwb, 49152L, 768, tokb, 1572864L, 768, 768,
      nullptr, nullptr, 0.03125f, 0,
      nullptr, 2048, 131072L, attnb, nullptr, nullptr, nullptr, rowsum);
  // 5. rw partials = w @ tokens (unnormalized), K-split x2
  k_routed_mfma<<<dim3(2, 12, 16), blk, 0, stream>>>(attnb, tokb, parts);
  // 6. sum parts -> rwb bf16
  k_sumcvt<<<dim3(768), blk, 0, stream>>>(parts, rwb);
  // 7. routed = rw @ W_proj + rowsum*b_proj  (M=1024, N=1024, K=768, mode 6)
  k_gemm64<<<dim3(16, 16, 1), blk, 0, stream>>>(
      rwb, 0L, 768, Wtp, 0L, 768, 768,
      nullptr, bp, 1.0f, 6,
      (void*)routed, 1024, 0L, nullptr, nullptr, rowsum, nullptr, nullptr);
  // 8. both LayerNorms
  k_ln2<<<dim3(2048), blk, 0, stream>>>(prev, routed, g_st, be_st, g_in, be_in,
                                        conc, candA);
  // 9. merged u|r gates (mode 5)
  k_gemm64<<<dim3(16, 32, 1), blk, 0, stream>>>(
      conc, 0L, 2048, Wtur, 0L, 2048, 2048,
      bu, br, 1.0f, 5,
      (void*)ubuf, 1024, 0L, candA, conc, nullptr, nullptr, nullptr);
  // 10. new_state (mode 3)
  k_gemm64<<<dim3(16, 16, 1), blk, 0, stream>>>(
      candA, 0L, 2048, Wtn, 0L, 2048, 2048,
      bn, nullptr, 1.0f, 3,
      (void*)ns, 1024, 0L, nullptr, nullptr, ubuf, prev, nullptr);
  // 11. final LN -> output
  k_ln_out<<<dim3(1024), blk, 0, stream>>>(ns, g_o, be_o, out);
}